// Round 3
// baseline (7841.912 us; speedup 1.0000x reference)
//
#include <hip/hip_runtime.h>
#include <math.h>

// ---------------------------------------------------------------------------
// LSTM-seq2seq + cross-attention + LN + FC head.
// fp32 LSTM/attention/LN; all large GEMMs (input gates, QKV, FC head) use
// split-bf16 3-term MFMA (a=ah+al, b=bh+bl; ah*bh+al*bh+ah*bl ~ fp32 precision,
// rel err ~1.5e-5) when ws_size permits, with per-tier fp32 fallback.
// Tier needs: FC 248.7MB, +QKV 278.1MB, +inputs 303.3MB.
// Sizes fixed per reference: V=32000 E=512 H=512 B=16 TE=TD=128 D=2H=1024.
// ---------------------------------------------------------------------------

#define B_   16
#define TE_  128
#define TD_  128
#define E_   512
#define H_   512
#define D_   1024      // 2H
#define V_   32000
#define GE_  2048      // 4H encoder gate width
#define GD_  4096      // 4D decoder gate width

__device__ __forceinline__ float sigm(float x) { return 1.f / (1.f + expf(-x)); }

// bf16 round-to-nearest-even helpers
__device__ __forceinline__ unsigned short f2bf(float x) {
  unsigned u = __float_as_uint(x);
  return (unsigned short)((u + 0x7FFFu + ((u >> 16) & 1u)) >> 16);
}
__device__ __forceinline__ float bf2f(unsigned short h) {
  return __uint_as_float((unsigned)h << 16);
}

// ---------------- zero (h/c state must be 0; ws is poisoned 0xAA) ----------
__global__ __launch_bounds__(256) void zero_kernel(float* __restrict__ p, int n) {
  int i = blockIdx.x * 256 + threadIdx.x;
  if (i < n) p[i] = 0.f;
}

// ---------------- 32x32 tiled transpose: out[C][R] = in[R][C] --------------
__global__ __launch_bounds__(256) void transpose_k(const float* __restrict__ in,
                                                   float* __restrict__ out,
                                                   int R, int C) {
  __shared__ float tile[32][33];
  int r0 = blockIdx.x * 32, c0 = blockIdx.y * 32;
  int tx = threadIdx.x & 31, ty = threadIdx.x >> 5;   // ty 0..7
#pragma unroll
  for (int i = 0; i < 4; ++i)
    tile[ty + i * 8][tx] = in[(long)(r0 + ty + i * 8) * C + c0 + tx];
  __syncthreads();
#pragma unroll
  for (int i = 0; i < 4; ++i)
    out[(long)(c0 + ty + i * 8) * R + r0 + tx] = tile[tx][ty + i * 8];
}

// ---------------- generic fp32 NT GEMM, optional row-gather on A -----------
// Fallback path only. C[m][n] = sum_k A[rowA(m)][k]*B[n][k] + bias1 + bias2.
__global__ __launch_bounds__(256) void gemm_nt(
    const float* __restrict__ A, const int* __restrict__ gather,
    const float* __restrict__ Bm, const float* __restrict__ bias1,
    const float* __restrict__ bias2, float* __restrict__ C,
    int M, int N, int K) {
  __shared__ float As[32][68];
  __shared__ float Bs[32][68];
  int n0 = blockIdx.x * 64, m0 = blockIdx.y * 64;
  int tid = threadIdx.x;
  int tx = tid & 15, ty = tid >> 4;
  float acc[4][4] = {};
  for (int k0 = 0; k0 < K; k0 += 32) {
#pragma unroll
    for (int i = 0; i < 2; ++i) {
      int qi = tid + i * 256;
      int m = qi >> 3, kv = qi & 7;
      long arow = gather ? (long)gather[m0 + m] : (long)(m0 + m);
      float4 va = *reinterpret_cast<const float4*>(A + arow * K + k0 + kv * 4);
      As[kv * 4 + 0][m] = va.x; As[kv * 4 + 1][m] = va.y;
      As[kv * 4 + 2][m] = va.z; As[kv * 4 + 3][m] = va.w;
      float4 vb = *reinterpret_cast<const float4*>(Bm + (long)(n0 + m) * K + k0 + kv * 4);
      Bs[kv * 4 + 0][m] = vb.x; Bs[kv * 4 + 1][m] = vb.y;
      Bs[kv * 4 + 2][m] = vb.z; Bs[kv * 4 + 3][m] = vb.w;
    }
    __syncthreads();
#pragma unroll
    for (int kk = 0; kk < 32; ++kk) {
      float4 a = *reinterpret_cast<const float4*>(&As[kk][ty * 4]);
      float4 b = *reinterpret_cast<const float4*>(&Bs[kk][tx * 4]);
      acc[0][0] = fmaf(a.x, b.x, acc[0][0]); acc[0][1] = fmaf(a.x, b.y, acc[0][1]);
      acc[0][2] = fmaf(a.x, b.z, acc[0][2]); acc[0][3] = fmaf(a.x, b.w, acc[0][3]);
      acc[1][0] = fmaf(a.y, b.x, acc[1][0]); acc[1][1] = fmaf(a.y, b.y, acc[1][1]);
      acc[1][2] = fmaf(a.y, b.z, acc[1][2]); acc[1][3] = fmaf(a.y, b.w, acc[1][3]);
      acc[2][0] = fmaf(a.z, b.x, acc[2][0]); acc[2][1] = fmaf(a.z, b.y, acc[2][1]);
      acc[2][2] = fmaf(a.z, b.z, acc[2][2]); acc[2][3] = fmaf(a.z, b.w, acc[2][3]);
      acc[3][0] = fmaf(a.w, b.x, acc[3][0]); acc[3][1] = fmaf(a.w, b.y, acc[3][1]);
      acc[3][2] = fmaf(a.w, b.z, acc[3][2]); acc[3][3] = fmaf(a.w, b.w, acc[3][3]);
    }
    __syncthreads();
  }
  float bb[4];
#pragma unroll
  for (int j = 0; j < 4; ++j) {
    float v = 0.f;
    if (bias1) v += bias1[n0 + tx * 4 + j];
    if (bias2) v += bias2[n0 + tx * 4 + j];
    bb[j] = v;
  }
#pragma unroll
  for (int i = 0; i < 4; ++i) {
    float4 o;
    o.x = acc[i][0] + bb[0]; o.y = acc[i][1] + bb[1];
    o.z = acc[i][2] + bb[2]; o.w = acc[i][3] + bb[3];
    *reinterpret_cast<float4*>(C + (long)(m0 + ty * 4 + i) * N + n0 + tx * 4) = o;
  }
}

// ---------------- fp32 -> (hi,lo) bf16 split, vectorized -------------------
__global__ __launch_bounds__(256) void split_bf16_kernel(
    const float* __restrict__ in, unsigned short* __restrict__ hi,
    unsigned short* __restrict__ lo, int n4) {
  int stride = gridDim.x * 256;
  for (int i = blockIdx.x * 256 + threadIdx.x; i < n4; i += stride) {
    float4 v = reinterpret_cast<const float4*>(in)[i];
    ushort4 h, l;
    h.x = f2bf(v.x); l.x = f2bf(v.x - bf2f(h.x));
    h.y = f2bf(v.y); l.y = f2bf(v.y - bf2f(h.y));
    h.z = f2bf(v.z); l.z = f2bf(v.z - bf2f(h.z));
    h.w = f2bf(v.w); l.w = f2bf(v.w - bf2f(h.w));
    reinterpret_cast<ushort4*>(hi)[i] = h;
    reinterpret_cast<ushort4*>(lo)[i] = l;
  }
}

// -------- embedding gather + split: rows seq[] of emb -> hi/lo [rows,512] --
__global__ __launch_bounds__(256) void gather_split_kernel(
    const float* __restrict__ emb, const int* __restrict__ seq,
    unsigned short* __restrict__ hi, unsigned short* __restrict__ lo, int n4) {
  int stride = gridDim.x * 256;
  for (int i = blockIdx.x * 256 + threadIdx.x; i < n4; i += stride) {
    int row = i >> 7, c4 = i & 127;                  // K=512 -> 128 float4/row
    float4 v = *reinterpret_cast<const float4*>(emb + (long)seq[row] * E_ + c4 * 4);
    ushort4 h, l;
    h.x = f2bf(v.x); l.x = f2bf(v.x - bf2f(h.x));
    h.y = f2bf(v.y); l.y = f2bf(v.y - bf2f(h.y));
    h.z = f2bf(v.z); l.z = f2bf(v.z - bf2f(h.z));
    h.w = f2bf(v.w); l.w = f2bf(v.w - bf2f(h.w));
    reinterpret_cast<ushort4*>(hi)[i] = h;
    reinterpret_cast<ushort4*>(lo)[i] = l;
  }
}

// ---------------- split-bf16 MFMA NT GEMM (m97 structure) ------------------
// C[m][n] = sum_k (Ah+Al)[m][k]*(Bh+Bl)[n][k] (3-term) + bias1[n] + bias2[n]
// 128x128 tile, BK=32, 256 thr = 4 waves each owning a 64x64 quadrant
// (4x4 frags of 16x16x32). Staging via global_load_lds width=16 (linear LDS,
// wave-uniform base + lane*16 -- m104 constraint respected).
typedef __attribute__((ext_vector_type(8))) short bf16x8;
typedef __attribute__((ext_vector_type(4))) float f32x4;

__device__ __forceinline__ void async16(void* lds, const void* g) {
  __builtin_amdgcn_global_load_lds(
      (const __attribute__((address_space(1))) unsigned int*)g,
      (__attribute__((address_space(3))) unsigned int*)lds, 16, 0, 0);
}

__global__ __launch_bounds__(256) void gemm_split3(
    const unsigned short* __restrict__ Ah, const unsigned short* __restrict__ Al,
    const unsigned short* __restrict__ Bh, const unsigned short* __restrict__ Bl,
    const float* __restrict__ bias1, const float* __restrict__ bias2,
    float* __restrict__ C, int M, int N, int K) {
  __shared__ unsigned short sAh[128 * 32], sAl[128 * 32];
  __shared__ unsigned short sBh[128 * 32], sBl[128 * 32];
  int tid = threadIdx.x;
  int lane = tid & 63, w = tid >> 6;
  int wr = w >> 1, wc = w & 1;             // wave -> 64x64 quadrant
  int n0 = blockIdx.x * 128, m0 = blockIdx.y * 128;
  int fr = lane & 15, fq = lane >> 4;      // frag row(col), k-group
  f32x4 acc[4][4] = {};
  for (int k0 = 0; k0 < K; k0 += 32) {
    // ---- stage 4 tiles (8KB each): chunk c -> row=c>>2, k8=(c&3)*8 ----
#pragma unroll
    for (int j = 0; j < 2; ++j) {
      int cbase = j * 256 + w * 64;        // wave-uniform
      int chunk = cbase + lane;
      int row = chunk >> 2, kk = (chunk & 3) * 8;
      long ga = (long)(m0 + row) * K + k0 + kk;
      long gb = (long)(n0 + row) * K + k0 + kk;
      async16(&sAh[cbase * 8], Ah + ga);
      async16(&sAl[cbase * 8], Al + ga);
      async16(&sBh[cbase * 8], Bh + gb);
      async16(&sBl[cbase * 8], Bl + gb);
    }
    __syncthreads();                        // compiler drains vmcnt before barrier
    // ---- fragments: A row=lane&15, k=(lane>>4)*8+j ; B symmetric (NT) ----
    bf16x8 ah[4], al[4], bh[4], bl[4];
#pragma unroll
    for (int m = 0; m < 4; ++m) {
      int r = (wr * 64 + m * 16 + fr) * 32 + fq * 8;
      ah[m] = *reinterpret_cast<const bf16x8*>(&sAh[r]);
      al[m] = *reinterpret_cast<const bf16x8*>(&sAl[r]);
    }
#pragma unroll
    for (int n = 0; n < 4; ++n) {
      int r = (wc * 64 + n * 16 + fr) * 32 + fq * 8;
      bh[n] = *reinterpret_cast<const bf16x8*>(&sBh[r]);
      bl[n] = *reinterpret_cast<const bf16x8*>(&sBl[r]);
    }
#pragma unroll
    for (int m = 0; m < 4; ++m)
#pragma unroll
      for (int n = 0; n < 4; ++n) {
        acc[m][n] = __builtin_amdgcn_mfma_f32_16x16x32_bf16(ah[m], bh[n], acc[m][n], 0, 0, 0);
        acc[m][n] = __builtin_amdgcn_mfma_f32_16x16x32_bf16(al[m], bh[n], acc[m][n], 0, 0, 0);
        acc[m][n] = __builtin_amdgcn_mfma_f32_16x16x32_bf16(ah[m], bl[n], acc[m][n], 0, 0, 0);
      }
    __syncthreads();
  }
  // ---- epilogue: C/D map (m89-verified): col=lane&15, row=(lane>>4)*4+reg --
#pragma unroll
  for (int m = 0; m < 4; ++m) {
    int r0 = m0 + wr * 64 + m * 16 + fq * 4;
#pragma unroll
    for (int n = 0; n < 4; ++n) {
      int col = n0 + wc * 64 + n * 16 + fr;
      float bv = 0.f;
      if (bias1) bv += bias1[col];
      if (bias2) bv += bias2[col];
#pragma unroll
      for (int jj = 0; jj < 4; ++jj)
        C[(long)(r0 + jj) * N + col] = acc[m][n][jj] + bv;
    }
  }
}

// ---------------- encoder LSTM, one time step, both directions -------------
// grid 256 = dir(2) x bg(2: 8 batches) x chunk(64: 8 hidden units) -> 1/CU.
// h double-buffered across launches (blocks of one launch may interleave);
// c single-buffered (each block exclusively owns its c slice).
// State layout is the decoder's concat layout: h[b][dir*H + hu].
__global__ __launch_bounds__(256) void lstm_enc_step(
    const float* __restrict__ xg_f, const float* __restrict__ xg_b,
    const float* __restrict__ whhT_f, const float* __restrict__ whhT_b,
    float* __restrict__ hbuf, float* __restrict__ cbuf,
    float* __restrict__ enc_out, int t) {
  int blk = blockIdx.x;
  int chunk = blk & 63;
  int bg = (blk >> 6) & 1;
  int dir = blk >> 7;
  const float* xg   = dir ? xg_b   : xg_f;
  const float* whhT = dir ? whhT_b : whhT_f;
  int tt = dir ? (TE_ - 1 - t) : t;
  const float* hread = hbuf + (t & 1) * (B_ * D_);
  float* hwrite      = hbuf + ((t + 1) & 1) * (B_ * D_);

  __shared__ float hs[8][512];     // h for 8 batches of this direction (16KB)
  __shared__ float gs[8][4][8];    // gate preacts (batch, i/f/g/o, hu)
  int tid = threadIdx.x;
#pragma unroll
  for (int i = 0; i < 4; ++i) {
    int qi = tid + i * 256;        // 1024 float4 slots
    int bsl = qi >> 7, e4 = qi & 127;
    *reinterpret_cast<float4*>(&hs[bsl][e4 * 4]) =
        *reinterpret_cast<const float4*>(hread + (bg * 8 + bsl) * D_ + dir * H_ + e4 * 4);
  }
  __syncthreads();

  int j = tid & 7, seg = (tid >> 3) & 3, bi = tid >> 5;   // bi 0..7
  int hu0 = chunk * 8;
  int gcol = seg * H_ + hu0 + j;                          // torch gate order i,f,g,o
  int b = bg * 8 + bi;
  float acc = xg[(long)(b * TE_ + tt) * GE_ + gcol];
  for (int e4 = 0; e4 < 128; ++e4) {
    float4 h0 = *reinterpret_cast<const float4*>(&hs[bi][e4 * 4]);
    const float* wp = whhT + (long)(e4 * 4) * GE_ + gcol;
    acc = fmaf(h0.x, wp[0], fmaf(h0.y, wp[GE_], fmaf(h0.z, wp[2 * GE_],
          fmaf(h0.w, wp[3 * GE_], acc))));
  }
  gs[bi][seg][j] = acc;
  __syncthreads();
  if (tid < 64) {
    int bsl = tid >> 3, jj = tid & 7;
    int b2 = bg * 8 + bsl;
    int hu = hu0 + jj;
    float gi = gs[bsl][0][jj], gf = gs[bsl][1][jj];
    float gg = gs[bsl][2][jj], go = gs[bsl][3][jj];
    float* cp = cbuf + b2 * D_ + dir * H_ + hu;
    float c = *cp;
    float cn = sigm(gf) * c + sigm(gi) * tanhf(gg);
    float hn = sigm(go) * tanhf(cn);
    *cp = cn;
    hwrite[b2 * D_ + dir * H_ + hu] = hn;
    enc_out[(long)(b2 * TE_ + tt) * D_ + dir * H_ + hu] = hn;
  }
}

// ---------------- decoder LSTM step (hidden = D = 1024) --------------------
// grid 256 = bg(2: 8 batches) x chunk(128: 8 hidden units) -> 1/CU.
__global__ __launch_bounds__(256) void lstm_dec_step(
    const float* __restrict__ xg_d, const float* __restrict__ whhT_d,
    float* __restrict__ hbuf, float* __restrict__ cbuf,
    float* __restrict__ dec_out, int t) {
  int blk = blockIdx.x;
  int chunk = blk & 127;
  int bg = blk >> 7;
  const float* hread = hbuf + (t & 1) * (B_ * D_);
  float* hwrite      = hbuf + ((t + 1) & 1) * (B_ * D_);
  __shared__ float hs[8][1024];    // 32 KB
  __shared__ float gs[8][4][8];
  int tid = threadIdx.x;
#pragma unroll
  for (int i = 0; i < 8; ++i) {
    int qi = tid + i * 256;        // 2048 float4 slots
    int bsl = qi >> 8, e4 = qi & 255;
    *reinterpret_cast<float4*>(&hs[bsl][e4 * 4]) =
        *reinterpret_cast<const float4*>(hread + (bg * 8 + bsl) * D_ + e4 * 4);
  }
  __syncthreads();
  int j = tid & 7, seg = (tid >> 3) & 3, bi = tid >> 5;
  int hu0 = chunk * 8;
  int gcol = seg * D_ + hu0 + j;
  int b = bg * 8 + bi;
  float acc = xg_d[(long)(b * TD_ + t) * GD_ + gcol];
  for (int e4 = 0; e4 < 256; ++e4) {
    float4 h0 = *reinterpret_cast<const float4*>(&hs[bi][e4 * 4]);
    const float* wp = whhT_d + (long)(e4 * 4) * GD_ + gcol;
    acc = fmaf(h0.x, wp[0], fmaf(h0.y, wp[GD_], fmaf(h0.z, wp[2 * GD_],
          fmaf(h0.w, wp[3 * GD_], acc))));
  }
  gs[bi][seg][j] = acc;
  __syncthreads();
  if (tid < 64) {
    int bsl = tid >> 3, jj = tid & 7;
    int b2 = bg * 8 + bsl;
    int hu = hu0 + jj;
    float gi = gs[bsl][0][jj], gf = gs[bsl][1][jj];
    float gg = gs[bsl][2][jj], go = gs[bsl][3][jj];
    float* cp = cbuf + b2 * D_ + hu;
    float c = *cp;
    float cn = sigm(gf) * c + sigm(gi) * tanhf(gg);
    float hn = sigm(go) * tanhf(cn);
    *cp = cn;
    hwrite[b2 * D_ + hu] = hn;
    dec_out[(long)(b2 * TD_ + t) * D_ + hu] = hn;
  }
}

// ---------------- fused attention: QK^T + mask + softmax + PV --------------
__global__ __launch_bounds__(256) void attn_kernel(
    const float* __restrict__ q, const float* __restrict__ k,
    const float* __restrict__ v, const int* __restrict__ encseq,
    float* __restrict__ ctx) {
  int b = blockIdx.x >> 4;
  int q0 = (blockIdx.x & 15) * 8;
  __shared__ float sim[8][129];
  __shared__ float ks[32][132];
  __shared__ float qs[32][8];
  __shared__ float pr[8][16];
  __shared__ float rowm[8];
  __shared__ float rowinv[8];
  int tid = threadIdx.x;
  int kt = tid & 127, qh = tid >> 7;
  float acc[4] = {0.f, 0.f, 0.f, 0.f};
  for (int e0 = 0; e0 < D_; e0 += 32) {
#pragma unroll
    for (int i = 0; i < 4; ++i) {
      int qi = tid + i * 256;
      int kr = qi >> 3, ev = qi & 7;
      float4 vv = *reinterpret_cast<const float4*>(k + (long)(b * TE_ + kr) * D_ + e0 + ev * 4);
      ks[ev * 4 + 0][kr] = vv.x; ks[ev * 4 + 1][kr] = vv.y;
      ks[ev * 4 + 2][kr] = vv.z; ks[ev * 4 + 3][kr] = vv.w;
    }
    if (tid < 64) {
      int qr = tid >> 3, ev = tid & 7;
      float4 vv = *reinterpret_cast<const float4*>(q + (long)(b * TD_ + q0 + qr) * D_ + e0 + ev * 4);
      qs[ev * 4 + 0][qr] = vv.x; qs[ev * 4 + 1][qr] = vv.y;
      qs[ev * 4 + 2][qr] = vv.z; qs[ev * 4 + 3][qr] = vv.w;
    }
    __syncthreads();
#pragma unroll
    for (int e = 0; e < 32; ++e) {
      float kv = ks[e][kt];
      acc[0] = fmaf(kv, qs[e][qh * 4 + 0], acc[0]);
      acc[1] = fmaf(kv, qs[e][qh * 4 + 1], acc[1]);
      acc[2] = fmaf(kv, qs[e][qh * 4 + 2], acc[2]);
      acc[3] = fmaf(kv, qs[e][qh * 4 + 3], acc[3]);
    }
    __syncthreads();
  }
  bool masked = (encseq[b * TE_ + kt] == 0);   // PAD==0
#pragma unroll
  for (int i = 0; i < 4; ++i)
    sim[qh * 4 + i][kt] = masked ? -1e30f : acc[i] * 0.03125f;  // /sqrt(1024)
  __syncthreads();
  if (tid < 128) {
    int r = tid >> 4, c = tid & 15;
    float m = -1e30f;
#pragma unroll
    for (int jj = 0; jj < 8; ++jj) m = fmaxf(m, sim[r][c + jj * 16]);
    pr[r][c] = m;
  }
  __syncthreads();
  if (tid < 8) {
    float m = -1e30f;
    for (int c = 0; c < 16; ++c) m = fmaxf(m, pr[tid][c]);
    rowm[tid] = m;
  }
  __syncthreads();
#pragma unroll
  for (int i = 0; i < 4; ++i) {
    int idx = tid + i * 256;
    int r = idx >> 7, c = idx & 127;
    sim[r][c] = expf(sim[r][c] - rowm[r]);
  }
  __syncthreads();
  if (tid < 128) {
    int r = tid >> 4, c = tid & 15;
    float s = 0.f;
#pragma unroll
    for (int jj = 0; jj < 8; ++jj) s += sim[r][c + jj * 16];
    pr[r][c] = s;
  }
  __syncthreads();
  if (tid < 8) {
    float s = 0.f;
    for (int c = 0; c < 16; ++c) s += pr[tid][c];
    rowinv[tid] = 1.f / s;
  }
  __syncthreads();
  int d0 = tid * 4;
  float a0[8], a1[8], a2[8], a3[8];
#pragma unroll
  for (int qi = 0; qi < 8; ++qi) { a0[qi] = a1[qi] = a2[qi] = a3[qi] = 0.f; }
  for (int kt2 = 0; kt2 < TE_; ++kt2) {
    float4 vv = *reinterpret_cast<const float4*>(v + (long)(b * TE_ + kt2) * D_ + d0);
#pragma unroll
    for (int qi = 0; qi < 8; ++qi) {
      float a = sim[qi][kt2];
      a0[qi] = fmaf(a, vv.x, a0[qi]); a1[qi] = fmaf(a, vv.y, a1[qi]);
      a2[qi] = fmaf(a, vv.z, a2[qi]); a3[qi] = fmaf(a, vv.w, a3[qi]);
    }
  }
#pragma unroll
  for (int qi = 0; qi < 8; ++qi) {
    float inv = rowinv[qi];
    float4 o; o.x = a0[qi] * inv; o.y = a1[qi] * inv; o.z = a2[qi] * inv; o.w = a3[qi] * inv;
    *reinterpret_cast<float4*>(ctx + (long)(b * TD_ + q0 + qi) * D_ + d0) = o;
  }
}

// ---------------- tanh(dec+ctx) + LayerNorm --------------------------------
__global__ __launch_bounds__(256) void ln_kernel(
    const float* __restrict__ dec_out, const float* __restrict__ ctx,
    const float* __restrict__ gamma, const float* __restrict__ beta,
    float* __restrict__ xln) {
  int row = blockIdx.x;
  int tid = threadIdx.x;
  __shared__ float wsum[4], wss[4], stat[2];
  float4 dv = *reinterpret_cast<const float4*>(dec_out + (long)row * D_ + tid * 4);
  float4 cv = *reinterpret_cast<const float4*>(ctx + (long)row * D_ + tid * 4);
  float x0 = tanhf(dv.x + cv.x), x1 = tanhf(dv.y + cv.y);
  float x2 = tanhf(dv.z + cv.z), x3 = tanhf(dv.w + cv.w);
  float s = x0 + x1 + x2 + x3;
  float qq = x0 * x0 + x1 * x1 + x2 * x2 + x3 * x3;
#pragma unroll
  for (int off = 32; off > 0; off >>= 1) {
    s += __shfl_down(s, off);
    qq += __shfl_down(qq, off);
  }
  if ((tid & 63) == 0) { wsum[tid >> 6] = s; wss[tid >> 6] = qq; }
  __syncthreads();
  if (tid == 0) {
    float S = wsum[0] + wsum[1] + wsum[2] + wsum[3];
    float Q2 = wss[0] + wss[1] + wss[2] + wss[3];
    float mu = S * (1.f / 1024.f);
    float var = Q2 * (1.f / 1024.f) - mu * mu;   // biased var, matches jnp.var
    stat[0] = mu; stat[1] = rsqrtf(var + 1e-5f);
  }
  __syncthreads();
  float mu = stat[0], rs = stat[1];
  int c = tid * 4;
  float4 g4 = *reinterpret_cast<const float4*>(gamma + c);
  float4 b4 = *reinterpret_cast<const float4*>(beta + c);
  float4 o;
  o.x = (x0 - mu) * rs * g4.x + b4.x;
  o.y = (x1 - mu) * rs * g4.y + b4.y;
  o.z = (x2 - mu) * rs * g4.z + b4.z;
  o.w = (x3 - mu) * rs * g4.w + b4.w;
  *reinterpret_cast<float4*>(xln + (long)row * D_ + c) = o;
}

// ---------------------------------------------------------------------------
extern "C" void kernel_launch(void* const* d_in, const int* in_sizes, int n_in,
                              void* d_out, int out_size, void* d_ws, size_t ws_size,
                              hipStream_t stream) {
  const int*   enc_seq = (const int*)d_in[0];
  const int*   dec_seq = (const int*)d_in[1];
  const float* enc_emb = (const float*)d_in[2];
  const float* dec_emb = (const float*)d_in[3];
  const float* Wih_f = (const float*)d_in[4];
  const float* Whh_f = (const float*)d_in[5];
  const float* bih_f = (const float*)d_in[6];
  const float* bhh_f = (const float*)d_in[7];
  const float* Wih_b = (const float*)d_in[8];
  const float* Whh_b = (const float*)d_in[9];
  const float* bih_b = (const float*)d_in[10];
  const float* bhh_b = (const float*)d_in[11];
  const float* Wih_d = (const float*)d_in[12];
  const float* Whh_d = (const float*)d_in[13];
  const float* bih_d = (const float*)d_in[14];
  const float* bhh_d = (const float*)d_in[15];
  const float* Wq  = (const float*)d_in[16];
  const float* bq  = (const float*)d_in[17];
  const float* Wk  = (const float*)d_in[18];
  const float* bk  = (const float*)d_in[19];
  const float* Wv  = (const float*)d_in[20];
  const float* bv  = (const float*)d_in[21];
  const float* Wfc = (const float*)d_in[22];
  const float* bfc = (const float*)d_in[23];
  const float* gamma = (const float*)d_in[24];
  const float* beta  = (const float*)d_in[25];
  float* out = (float*)d_out;
  float* ws  = (float*)d_ws;

  // ---- workspace: baseline aliased layout (27.31M floats = 109.2MB) ----
  size_t off = 0;
  float* xg_f    = ws + off; off += (size_t)B_ * TE_ * GE_;
  float* xg_b    = ws + off; off += (size_t)B_ * TE_ * GE_;
  float* xg_d    = ws + off; off += (size_t)B_ * TD_ * GD_;
  float* whhT_f  = ws + off; off += (size_t)H_ * GE_;
  float* whhT_b  = ws + off; off += (size_t)H_ * GE_;
  float* whhT_d  = ws + off; off += (size_t)D_ * GD_;
  float* enc_out = ws + off; off += (size_t)B_ * TE_ * D_;
  float* dec_out = ws + off; off += (size_t)B_ * TD_ * D_;
  float* hbuf    = ws + off; off += 2 * B_ * D_;
  float* cbuf    = ws + off; off += B_ * D_;
  // dead-buffer aliases (lifetimes verified against launch order):
  float* qb  = xg_f;                               // written after decoder
  float* kb  = xg_f + (size_t)B_ * TD_ * D_;       // written after encoder
  float* vb  = xg_b;
  float* ctx = xg_b + (size_t)B_ * TD_ * D_;
  float* xln = xg_d;                               // written after decoder

  // ---- tiered split-bf16 buffers (ushort), priority FC > QKV > inputs ----
  unsigned short* up = (unsigned short*)(ws + off);
  size_t ubase = off * sizeof(float);
  const size_t NK = (size_t)V_ * D_;               // Wfc elems
  const size_t MK = (size_t)(B_ * TD_) * D_;       // 2048x1024 elems
  const size_t WD = (size_t)D_ * D_;               // Wq/Wk/Wv elems
  const size_t XE = (size_t)(B_ * TE_) * E_;       // gathered emb elems
  const size_t WE1 = (size_t)GE_ * E_;             // Wih_f/b elems
  const size_t WE2 = (size_t)GD_ * E_;             // Wih_d elems
  size_t uo = 0;
  // tier 1: FC head
  unsigned short* FCh = up + uo; uo += NK;
  unsigned short* FCl = up + uo; uo += NK;
  unsigned short* Xh  = up + uo; uo += MK;         // xln split
  unsigned short* Xl  = up + uo; uo += MK;
  const size_t need1 = ubase + uo * sizeof(unsigned short);
  // tier 2: QKV
  unsigned short* Qwh = up + uo; uo += WD;
  unsigned short* Qwl = up + uo; uo += WD;
  unsigned short* Kwh = up + uo; uo += WD;
  unsigned short* Kwl = up + uo; uo += WD;
  unsigned short* Vwh = up + uo; uo += WD;
  unsigned short* Vwl = up + uo; uo += WD;
  unsigned short* Eh  = up + uo; uo += MK;         // enc_out split
  unsigned short* El  = up + uo; uo += MK;
  unsigned short* Dh  = up + uo; uo += MK;         // dec_out split
  unsigned short* Dl  = up + uo; uo += MK;
  const size_t need2 = ubase + uo * sizeof(unsigned short);
  // tier 3: input gate GEMMs
  unsigned short* XEh = up + uo; uo += XE;         // gathered enc emb split
  unsigned short* XEl = up + uo; uo += XE;
  unsigned short* XDh = up + uo; uo += XE;         // gathered dec emb split
  unsigned short* XDl = up + uo; uo += XE;
  unsigned short* WFh = up + uo; uo += WE1;
  unsigned short* WFl = up + uo; uo += WE1;
  unsigned short* WBh = up + uo; uo += WE1;
  unsigned short* WBl = up + uo; uo += WE1;
  unsigned short* WDh = up + uo; uo += WE2;
  unsigned short* WDl = up + uo; uo += WE2;
  const size_t need3 = ubase + uo * sizeof(unsigned short);
  // ws_size constant per process -> branches are graph-safe
  const bool t1 = (ws_size >= need1);
  const bool t2 = (ws_size >= need2);
  const bool t3 = (ws_size >= need3);

  dim3 thr(256);

  zero_kernel<<<dim3(192), thr, 0, stream>>>(hbuf, 3 * B_ * D_);

  transpose_k<<<dim3(GE_ / 32, H_ / 32), thr, 0, stream>>>(Whh_f, whhT_f, GE_, H_);
  transpose_k<<<dim3(GE_ / 32, H_ / 32), thr, 0, stream>>>(Whh_b, whhT_b, GE_, H_);
  transpose_k<<<dim3(GD_ / 32, D_ / 32), thr, 0, stream>>>(Whh_d, whhT_d, GD_, D_);

  // ---- input-side gate GEMMs (fused embedding gather, + both biases) ----
  if (t3) {
    gather_split_kernel<<<dim3(256), thr, 0, stream>>>(enc_emb, enc_seq, XEh, XEl, (int)(XE / 4));
    gather_split_kernel<<<dim3(256), thr, 0, stream>>>(dec_emb, dec_seq, XDh, XDl, (int)(XE / 4));
    split_bf16_kernel<<<dim3(512), thr, 0, stream>>>(Wih_f, WFh, WFl, (int)(WE1 / 4));
    split_bf16_kernel<<<dim3(512), thr, 0, stream>>>(Wih_b, WBh, WBl, (int)(WE1 / 4));
    split_bf16_kernel<<<dim3(512), thr, 0, stream>>>(Wih_d, WDh, WDl, (int)(WE2 / 4));
    gemm_split3<<<dim3(GE_ / 128, 16), thr, 0, stream>>>(XEh, XEl, WFh, WFl, bih_f, bhh_f,
                                                         xg_f, 2048, GE_, E_);
    gemm_split3<<<dim3(GE_ / 128, 16), thr, 0, stream>>>(XEh, XEl, WBh, WBl, bih_b, bhh_b,
                                                         xg_b, 2048, GE_, E_);
    gemm_split3<<<dim3(GD_ / 128, 16), thr, 0, stream>>>(XDh, XDl, WDh, WDl, bih_d, bhh_d,
                                                         xg_d, 2048, GD_, E_);
  } else {
    gemm_nt<<<dim3(GE_ / 64, 32), thr, 0, stream>>>(enc_emb, enc_seq, Wih_f, bih_f, bhh_f,
                                                    xg_f, 2048, GE_, E_);
    gemm_nt<<<dim3(GE_ / 64, 32), thr, 0, stream>>>(enc_emb, enc_seq, Wih_b, bih_b, bhh_b,
                                                    xg_b, 2048, GE_, E_);
    gemm_nt<<<dim3(GD_ / 64, 32), thr, 0, stream>>>(dec_emb, dec_seq, Wih_d, bih_d, bhh_d,
                                                    xg_d, 2048, GD_, E_);
  }

  // ---- encoder: 128 sequential steps, both directions per launch ----
  for (int t = 0; t < TE_; ++t)
    lstm_enc_step<<<dim3(256), thr, 0, stream>>>(xg_f, xg_b, whhT_f, whhT_b,
                                                 hbuf, cbuf, enc_out, t);
  // final (h,c) already sit in hbuf[0]/cbuf in decoder concat layout

  // ---- K/V projections ----
  if (t2) {
    split_bf16_kernel<<<dim3(512), thr, 0, stream>>>(Wk, Kwh, Kwl, (int)(WD / 4));
    split_bf16_kernel<<<dim3(512), thr, 0, stream>>>(Wv, Vwh, Vwl, (int)(WD / 4));
    split_bf16_kernel<<<dim3(512), thr, 0, stream>>>(Wq, Qwh, Qwl, (int)(WD / 4));
    split_bf16_kernel<<<dim3(512), thr, 0, stream>>>(enc_out, Eh, El, (int)(MK / 4));
    gemm_split3<<<dim3(D_ / 128, 16), thr, 0, stream>>>(Eh, El, Kwh, Kwl, bk, nullptr,
                                                        kb, 2048, D_, D_);
    gemm_split3<<<dim3(D_ / 128, 16), thr, 0, stream>>>(Eh, El, Vwh, Vwl, bv, nullptr,
                                                        vb, 2048, D_, D_);
  } else {
    gemm_nt<<<dim3(D_ / 64, 32), thr, 0, stream>>>(enc_out, nullptr, Wk, bk, nullptr,
                                                   kb, 2048, D_, D_);
    gemm_nt<<<dim3(D_ / 64, 32), thr, 0, stream>>>(enc_out, nullptr, Wv, bv, nullptr,
                                                   vb, 2048, D_, D_);
  }

  // ---- decoder: 128 sequential steps ----
  for (int t = 0; t < TD_; ++t)
    lstm_dec_step<<<dim3(256), thr, 0, stream>>>(xg_d, whhT_d, hbuf, cbuf, dec_out, t);

  // ---- Q projection ----
  if (t2) {
    split_bf16_kernel<<<dim3(512), thr, 0, stream>>>(dec_out, Dh, Dl, (int)(MK / 4));
    gemm_split3<<<dim3(D_ / 128, 16), thr, 0, stream>>>(Dh, Dl, Qwh, Qwl, bq, nullptr,
                                                        qb, 2048, D_, D_);
  } else {
    gemm_nt<<<dim3(D_ / 64, 32), thr, 0, stream>>>(dec_out, nullptr, Wq, bq, nullptr,
                                                   qb, 2048, D_, D_);
  }

  attn_kernel<<<dim3(256), thr, 0, stream>>>(qb, kb, vb, enc_seq, ctx);

  ln_kernel<<<dim3(2048), thr, 0, stream>>>(dec_out, ctx, gamma, beta, xln);

  // ---- FC head: [2048,1024]@[1024,32000] + bfc -> d_out ----
  if (t1) {
    split_bf16_kernel<<<dim3(2048), thr, 0, stream>>>(Wfc, FCh, FCl, (int)(NK / 4));
    split_bf16_kernel<<<dim3(512), thr, 0, stream>>>(xln, Xh, Xl, (int)(MK / 4));
    gemm_split3<<<dim3(V_ / 128, 2048 / 128), thr, 0, stream>>>(Xh, Xl, FCh, FCl, bfc, nullptr,
                                                                out, 2048, V_, D_);
  } else {
    gemm_nt<<<dim3(V_ / 64, 32), thr, 0, stream>>>(xln, nullptr, Wfc, bfc, nullptr,
                                                   out, 2048, V_, D_);
  }
}